// Round 4
// 513.033 us; speedup vs baseline: 1.0362x; 1.0362x over previous
//
#include <hip/hip_runtime.h>
#include <stdint.h>

// TopKAbsolutes2D — v2 "single-read" pipeline. B=64 rows, N=1,048,576/row, K=256.
//
// r0 evidence: harness fills run at 6.5 TB/s while our 4-pass pipeline moved
// ~768 MB in 531 us (~1.4 TB/s effective) -> structure-bound, not BW-bound.
// v2: (a) out zeroed by DMA fill (hipMemsetAsync), writes become sparse;
//     (b) x read exactly once: tail-only hist (bin>=2048, |x|>=2.0, ~4.5% of
//         elems do LDS atomics) + candidate collect (bin>=2052, |x|>=2.5,
//         ~1.2% ~ 12.4K/row) staged in LDS, 1 global atomic per block;
//     (c) top-K scattered sparsely from the candidate list;
//     (d) exact tie-break (abs desc, idx asc) unchanged.
// Per-row monolithic fallback (full re-read + 4096-bin hist) covers any data
// where tail assumptions fail (never for N(0,1) with >100-sigma margins).
//
// Discipline: all ws usage derived from ws_size; only the 3 counter arrays
// accumulate -> zeroed via one 768-B memset each call.
// (r1–r3 were GPUAcquisitionTimeouts — this source is the r0 proposal, resubmitted.)

#define NBINS   4096          // full bin space: 8 exp bits + 4 mantissa bits
#define TBINS   2048          // tail bins histogrammed in pass A: 2048..4095
#define TB_BASE 2048u         // bin(|x|=2.0)
#define G_COLLECT 2052u       // collect candidates with bin >= 2052 (|x|>=2.5)
#define ROWS  64
#define HBLK  8               // hist/collect blocks per row
#define CBLK  4               // compact blocks per row
#define LC_CAP 4096           // per-block LDS candidate staging (expect ~1630)
#define LDS_SEL 2048

// Pass A: one streaming read of x. Tail histogram into LDS (TBINS bins),
// candidates (bin >= G_COLLECT) appended to LDS buffer, bulk-flushed with one
// global atomicAdd per block. No global atomics per element.
__global__ __launch_bounds__(512) void hist_collect_kernel(
    const float* __restrict__ x, unsigned* __restrict__ parts,
    unsigned* __restrict__ cand_count, uint2* __restrict__ cand, unsigned cap1,
    unsigned* __restrict__ row_over, int n_per_row)
{
    __shared__ unsigned lh[TBINS];     // 8 KB
    __shared__ uint2 lc[LC_CAP];       // 32 KB
    __shared__ unsigned lcnt;
    __shared__ unsigned gbase;
    for (int i = threadIdx.x; i < TBINS; i += blockDim.x) lh[i] = 0;
    if (threadIdx.x == 0) lcnt = 0;
    __syncthreads();

    int row = blockIdx.x / HBLK;
    int sub = blockIdx.x % HBLK;
    int chunk = n_per_row / HBLK;                       // 131072 elems
    const float4* xv = (const float4*)(x + (size_t)row * n_per_row + (size_t)sub * chunk);
    unsigned idx_base = (unsigned)(sub * chunk);
    int nvec = chunk / 4;
    for (int i = threadIdx.x; i < nvec; i += blockDim.x) {
        float4 v = xv[i];
        unsigned bb[4] = {__float_as_uint(v.x), __float_as_uint(v.y),
                          __float_as_uint(v.z), __float_as_uint(v.w)};
        #pragma unroll
        for (int c = 0; c < 4; ++c) {
            unsigned bin = (bb[c] & 0x7fffffffu) >> 19;
            if (bin >= TB_BASE) {                       // ~4.5% of elements
                atomicAdd(&lh[bin - TB_BASE], 1u);
                if (bin >= G_COLLECT) {                 // ~1.2% of elements
                    unsigned pos = atomicAdd(&lcnt, 1u);
                    if (pos < (unsigned)LC_CAP)
                        lc[pos] = make_uint2(bb[c],
                                             idx_base + (unsigned)i * 4u + (unsigned)c);
                }
            }
        }
    }
    __syncthreads();

    // flush tail histogram (plain stores, per-block slab)
    unsigned* gp = parts + (size_t)blockIdx.x * TBINS;
    for (int i = threadIdx.x; i < TBINS; i += blockDim.x) gp[i] = lh[i];

    // flush candidates: one global atomic per block
    unsigned n = lcnt;
    if (threadIdx.x == 0) {
        unsigned nn = (n > (unsigned)LC_CAP) ? (unsigned)LC_CAP : n;
        gbase = atomicAdd(&cand_count[row], nn);
        if (n > (unsigned)LC_CAP || gbase + nn > cap1) atomicOr(&row_over[row], 1u);
    }
    if (n > (unsigned)LC_CAP) n = (unsigned)LC_CAP;
    __syncthreads();
    unsigned base = gbase;
    for (unsigned i = threadIdx.x; i < n; i += blockDim.x) {
        unsigned p = base + i;
        if (p < cap1) cand[(size_t)row * cap1 + p] = lc[i];
    }
}

// Pass B: per-row reduce of HBLK tail-hist slabs; find cutoff bin b* and
// r = K - count_above. ok := cutoff resolvable from the collected tail.
__global__ __launch_bounds__(256) void cutoff_kernel(
    const unsigned* __restrict__ parts, const int* __restrict__ topk,
    const unsigned* __restrict__ row_over,
    unsigned* __restrict__ row_b, unsigned* __restrict__ row_r,
    unsigned* __restrict__ row_ok)
{
    __shared__ unsigned h[TBINS];
    __shared__ unsigned csum[256];
    int row = blockIdx.x;
    const unsigned* base = parts + (size_t)row * HBLK * TBINS;
    for (int i = threadIdx.x; i < TBINS; i += blockDim.x) {
        unsigned s = 0;
        #pragma unroll
        for (int p = 0; p < HBLK; ++p) s += base[(size_t)p * TBINS + i];
        h[i] = s;
    }
    __syncthreads();

    const int CHUNK = TBINS / 256;                      // 8 bins per thread
    unsigned cs = 0;
    int cbase = threadIdx.x * CHUNK;
    #pragma unroll
    for (int j = 0; j < CHUNK; ++j) cs += h[cbase + j];
    csum[threadIdx.x] = cs;
    __syncthreads();

    if (threadIdx.x == 0) {
        unsigned K = (unsigned)(*topk);
        unsigned acc = 0;
        int found = 0, ch;
        for (ch = 255; ch >= 0; --ch) {
            if (acc + csum[ch] >= K) { found = 1; break; }
            acc += csum[ch];
        }
        unsigned okf = 0;
        if (found) {
            int b = ch * CHUNK + CHUNK - 1;
            for (; b > ch * CHUNK; --b) {
                unsigned c = h[b];
                if (acc + c >= K) break;
                acc += c;
            }
            unsigned bstar = (unsigned)b + TB_BASE;
            row_b[row] = bstar;
            row_r[row] = K - acc;                       // acc = count strictly above b*
            okf = (bstar >= G_COLLECT && row_over[row] == 0) ? 1u : 0u;
        }
        row_ok[row] = okf;                              // !found -> fallback recomputes
    }
}

// Pass C: stream candidate list (~12.4K/row): bin > b* -> scatter into out;
// bin == b* -> compact into cand2 for exact selection.
__global__ __launch_bounds__(256) void compact_kernel(
    const unsigned* __restrict__ cand_count, const uint2* __restrict__ cand,
    unsigned cap1, const unsigned* __restrict__ row_ok,
    const unsigned* __restrict__ row_b,
    unsigned* __restrict__ cand2_count, uint2* __restrict__ cand2, unsigned cap2,
    float* __restrict__ out, int n_per_row)
{
    int row = blockIdx.x / CBLK;
    if (!row_ok[row]) return;
    unsigned bstar = row_b[row];
    unsigned M = cand_count[row]; if (M > cap1) M = cap1;
    const uint2* c = cand + (size_t)row * cap1;
    int sub = blockIdx.x % CBLK;
    for (unsigned i = (unsigned)sub * blockDim.x + threadIdx.x; i < M;
         i += blockDim.x * CBLK) {
        uint2 e = c[i];
        unsigned bin = (e.x & 0x7fffffffu) >> 19;
        if (bin > bstar) {
            out[(size_t)row * n_per_row + e.y] = __uint_as_float(e.x);
        } else if (bin == bstar) {
            unsigned pos = atomicAdd(&cand2_count[row], 1u);
            if (pos < cap2) cand2[(size_t)row * cap2 + pos] = e;
        }
    }
}

// Pass D: monolithic per-row fallback (one block/row). No-op when row_ok.
// Full 4096-bin hist + cutoff + collect for rows the tail path couldn't serve.
__global__ __launch_bounds__(256) void fallback_kernel(
    const float* __restrict__ x, const int* __restrict__ topk,
    const unsigned* __restrict__ row_ok, unsigned* __restrict__ row_r,
    unsigned* __restrict__ cand2_count, uint2* __restrict__ cand2, unsigned cap2,
    float* __restrict__ out, int n_per_row)
{
    __shared__ unsigned h[NBINS];
    __shared__ unsigned csum[256];
    __shared__ unsigned sb;
    int row = blockIdx.x;
    if (row_ok[row]) return;

    for (int i = threadIdx.x; i < NBINS; i += blockDim.x) h[i] = 0;
    __syncthreads();
    const float* xr = x + (size_t)row * n_per_row;
    for (int i = threadIdx.x; i < n_per_row; i += blockDim.x)
        atomicAdd(&h[(__float_as_uint(xr[i]) & 0x7fffffffu) >> 19], 1u);
    __syncthreads();

    const int CHUNK = NBINS / 256;                      // 16
    unsigned cs = 0;
    for (int j = 0; j < CHUNK; ++j) cs += h[threadIdx.x * CHUNK + j];
    csum[threadIdx.x] = cs;
    __syncthreads();

    if (threadIdx.x == 0) {
        unsigned K = (unsigned)(*topk);
        unsigned acc = 0;
        int ch = 255;
        for (; ch > 0; --ch) { if (acc + csum[ch] >= K) break; acc += csum[ch]; }
        int b = ch * CHUNK + CHUNK - 1;
        for (; b > ch * CHUNK; --b) {
            unsigned c = h[b];
            if (acc + c >= K) break;
            acc += c;
        }
        sb = (unsigned)b;
        row_r[row] = K - acc;
    }
    __syncthreads();

    unsigned bstar = sb;
    for (int i = threadIdx.x; i < n_per_row; i += blockDim.x) {
        unsigned bits = __float_as_uint(xr[i]);
        unsigned bin = (bits & 0x7fffffffu) >> 19;
        if (bin > bstar) {
            out[(size_t)row * n_per_row + i] = __uint_as_float(bits);
        } else if (bin == bstar) {
            unsigned pos = atomicAdd(&cand2_count[row], 1u);
            if (pos < cap2) cand2[(size_t)row * cap2 + pos] = make_uint2(bits, (unsigned)i);
        }
    }
}

// Pass E: exact top-r among bin==b* candidates (abs desc, idx asc — matches
// jax.lax.top_k tie-breaking), scatter into out. Identical logic to v1.
__global__ __launch_bounds__(256) void select_kernel(
    const unsigned* __restrict__ cand2_count, const uint2* __restrict__ cand2,
    unsigned cap2, const unsigned* __restrict__ row_r,
    float* __restrict__ out, int n_per_row)
{
    __shared__ uint2 lc[LDS_SEL];
    int row = blockIdx.x;
    unsigned M = cand2_count[row];
    if (M > cap2) M = cap2;
    unsigned r = row_r[row];
    const uint2* c = cand2 + (size_t)row * cap2;
    if (M <= LDS_SEL) {
        for (unsigned i = threadIdx.x; i < M; i += blockDim.x) lc[i] = c[i];
        __syncthreads();
        for (unsigned i = threadIdx.x; i < M; i += blockDim.x) {
            uint2 ci = lc[i];
            unsigned ai = ci.x & 0x7fffffffu;
            unsigned rank = 0;
            for (unsigned j = 0; j < M; ++j) {
                uint2 cj = lc[j];
                unsigned aj = cj.x & 0x7fffffffu;
                rank += (unsigned)((aj > ai) || (aj == ai && cj.y < ci.y));
            }
            if (rank < r)
                out[(size_t)row * n_per_row + ci.y] = __uint_as_float(ci.x);
        }
    } else {
        for (unsigned i = threadIdx.x; i < M; i += blockDim.x) {
            uint2 ci = c[i];
            unsigned ai = ci.x & 0x7fffffffu;
            unsigned rank = 0;
            for (unsigned j = 0; j < M; ++j) {
                uint2 cj = c[j];
                unsigned aj = cj.x & 0x7fffffffu;
                rank += (unsigned)((aj > ai) || (aj == ai && cj.y < ci.y));
            }
            if (rank < r)
                out[(size_t)row * n_per_row + ci.y] = __uint_as_float(ci.x);
        }
    }
}

extern "C" void kernel_launch(void* const* d_in, const int* in_sizes, int n_in,
                              void* d_out, int out_size, void* d_ws, size_t ws_size,
                              hipStream_t stream) {
    const float* x  = (const float*)d_in[0];
    const int* topk = (const int*)d_in[1];
    float* out      = (float*)d_out;

    const int rows = ROWS;
    const int n_per_row = out_size / rows;              // 1,048,576 elements/row

    // --- workspace layout (strictly within ws_size) ---
    uint8_t* ws = (uint8_t*)d_ws;
    size_t off = 0;
    unsigned* parts = (unsigned*)(ws + off);
    off += (size_t)rows * HBLK * TBINS * sizeof(unsigned);        // 4 MiB
    // the 3 accumulating counter arrays — contiguous, zeroed by ONE 768-B memset
    unsigned* cand_count  = (unsigned*)(ws + off); off += 256;
    unsigned* cand2_count = (unsigned*)(ws + off); off += 256;
    unsigned* row_over    = (unsigned*)(ws + off); off += 256;
    // fully overwritten each call — no zeroing needed
    unsigned* row_b       = (unsigned*)(ws + off); off += 256;
    unsigned* row_r       = (unsigned*)(ws + off); off += 256;
    unsigned* row_ok      = (unsigned*)(ws + off); off += 256;
    off = (off + 255) & ~(size_t)255;

    size_t avail = (ws_size > off) ? (ws_size - off) : 0;
    size_t entries = avail / ((size_t)rows * sizeof(uint2));      // per-row budget
    unsigned cap1 = 32768u, cap2 = 16384u;                        // ~24 MiB total
    if (entries < (size_t)(cap1 + cap2)) {                        // degrade safely
        cap2 = (unsigned)(entries / 3); if (cap2 == 0) cap2 = 1;
        cap1 = (unsigned)(entries - cap2); if (cap1 == 0) cap1 = 1;
    }
    uint2* cand  = (uint2*)(ws + off); off += (size_t)rows * cap1 * sizeof(uint2);
    uint2* cand2 = (uint2*)(ws + off);

    // zero accumulators + the full output (DMA fill at ~81% of peak BW)
    hipMemsetAsync((void*)cand_count, 0, 768, stream);
    hipMemsetAsync((void*)out, 0, (size_t)out_size * sizeof(float), stream);

    hist_collect_kernel<<<rows * HBLK, 512, 0, stream>>>(x, parts, cand_count, cand,
                                                         cap1, row_over, n_per_row);
    cutoff_kernel<<<rows, 256, 0, stream>>>(parts, topk, row_over, row_b, row_r, row_ok);
    compact_kernel<<<rows * CBLK, 256, 0, stream>>>(cand_count, cand, cap1, row_ok,
                                                    row_b, cand2_count, cand2, cap2,
                                                    out, n_per_row);
    fallback_kernel<<<rows, 256, 0, stream>>>(x, topk, row_ok, row_r,
                                              cand2_count, cand2, cap2, out, n_per_row);
    select_kernel<<<rows, 256, 0, stream>>>(cand2_count, cand2, cap2, row_r,
                                            out, n_per_row);
}

// Round 5
// 507.151 us; speedup vs baseline: 1.0483x; 1.0116x over previous
//
#include <hip/hip_runtime.h>
#include <stdint.h>

// TopKAbsolutes2D — v3 "floor" pipeline. B=64 rows, N=1,048,576/row, K=256.
//
// r4 evidence: removing 512 MB of traffic (v1->v2) moved dur_us only -18.6 us;
// top-5 dispatches are all harness 1-GiB poison fills (~163 us @ 6.5 TB/s).
// => ~408 us of dur_us is fixed harness cost; controllable part ~105 us with a
// ~79 us traffic floor (read 256 MB + write 256 MB). v3 drives toward the floor:
//   - out zeroed inside the hist pass (fused read+zero-write, 1 pass, no memset)
//   - per-block cand slabs + counts: plain stores, ZERO global atomics,
//     ZERO memsets (nothing accumulates across calls)
//   - TBINS=512 with clamp-to-top-bin (exact: bin is a monotone coarsening of
//     |x|; final selection compares full absbits) -> parts 1 MiB
//   - compact+select fused into one per-row block (no cand2 buffer)
//   - 4 dispatches total (was 7)
// Exact multi-level fallback (12b hist -> +11b -> +8b -> ordered index scan)
// guarantees correctness for ANY input; early-exits for N(0,1) data.

#define TBINS   512           // tail bins: 2048..2559  (|x| in [2.0, 2^33))
#define TB_BASE 2048u         // bin(|x|=2.0)
#define TOPBIN  (TB_BASE + TBINS - 1)   // clamp bin (monotone coarsening)
#define G_COLLECT 2052u       // collect candidates with bin >= 2052 (|x|>=2.5)
#define ROWS  64
#define HBLK  8               // hist blocks per row
#define NBLKS (ROWS * HBLK)   // 512
#define CAP_DEF 4096u         // per-block LDS/global cand capacity (expect ~1630)
#define LDS_SEL 2048
#define OVERFLAG 0x80000000u

__device__ inline unsigned clamped_bin(unsigned bits) {
    unsigned b = (bits & 0x7fffffffu) >> 19;
    return b > TOPBIN ? TOPBIN : b;
}

// exact top-r among sel[0..M) by (|x| desc, idx asc) — matches jax.lax.top_k
__device__ inline void rank_select(const uint2* sel, unsigned M, unsigned r,
                                   float* orow) {
    for (unsigned i = threadIdx.x; i < M; i += blockDim.x) {
        uint2 ci = sel[i];
        unsigned ai = ci.x & 0x7fffffffu;
        unsigned rank = 0;
        for (unsigned j = 0; j < M; ++j) {
            uint2 cj = sel[j];
            unsigned aj = cj.x & 0x7fffffffu;
            rank += (unsigned)((aj > ai) || (aj == ai && cj.y < ci.y));
        }
        if (rank < r) orow[ci.y] = __uint_as_float(ci.x);
    }
}

// Pass A: ONE streaming pass: read x, write zeros to out (dense), tail hist
// (512 bins, clamped) in LDS, candidates (bin>=G_COLLECT) staged in LDS.
// Flush: per-block slab + per-block count — plain stores, no global atomics.
__global__ __launch_bounds__(512) void hist_collect_kernel(
    const float* __restrict__ x, float* __restrict__ out,
    unsigned* __restrict__ parts, unsigned* __restrict__ bcount,
    uint2* __restrict__ cand, unsigned cap, int n_per_row)
{
    __shared__ unsigned lh[TBINS];       // 2 KB
    __shared__ uint2 lc[CAP_DEF];        // 32 KB
    __shared__ unsigned lcnt;
    for (int i = threadIdx.x; i < TBINS; i += blockDim.x) lh[i] = 0;
    if (threadIdx.x == 0) lcnt = 0;
    __syncthreads();

    int row = blockIdx.x / HBLK;
    int sub = blockIdx.x % HBLK;
    int chunk = n_per_row / HBLK;                        // 131072 elems
    size_t base_e = (size_t)row * n_per_row + (size_t)sub * chunk;
    const float4* xv = (const float4*)(x + base_e);
    float4* ov = (float4*)(out + base_e);
    unsigned idx_base = (unsigned)(sub * chunk);
    const float4 z = make_float4(0.f, 0.f, 0.f, 0.f);
    int nvec = chunk / 4;
    for (int i = threadIdx.x; i < nvec; i += blockDim.x) {
        float4 v = xv[i];
        ov[i] = z;                                       // fused dense zero-write
        unsigned bb[4] = {__float_as_uint(v.x), __float_as_uint(v.y),
                          __float_as_uint(v.z), __float_as_uint(v.w)};
        #pragma unroll
        for (int c = 0; c < 4; ++c) {
            unsigned cb = clamped_bin(bb[c]);
            if (cb >= TB_BASE) {                         // ~4.5% of elements
                atomicAdd(&lh[cb - TB_BASE], 1u);        // LDS atomic only
                if (cb >= G_COLLECT) {                   // ~1.2% of elements
                    unsigned pos = atomicAdd(&lcnt, 1u);
                    if (pos < CAP_DEF)
                        lc[pos] = make_uint2(bb[c],
                                             idx_base + (unsigned)i * 4u + (unsigned)c);
                }
            }
        }
    }
    __syncthreads();

    unsigned* gp = parts + (size_t)blockIdx.x * TBINS;   // per-block slab
    for (int i = threadIdx.x; i < TBINS; i += blockDim.x) gp[i] = lh[i];

    unsigned n = lcnt;
    unsigned lim = (cap < CAP_DEF) ? cap : CAP_DEF;
    unsigned nn = (n > lim) ? lim : n;
    if (threadIdx.x == 0)
        bcount[blockIdx.x] = nn | ((n > lim) ? OVERFLAG : 0u);   // plain store
    uint2* cp = cand + (size_t)blockIdx.x * cap;
    for (unsigned i = threadIdx.x; i < nn; i += blockDim.x) cp[i] = lc[i];
}

// Pass B: per-row reduce of HBLK 512-bin slabs -> b*, r, ok. Plain stores only.
__global__ __launch_bounds__(256) void cutoff_kernel(
    const unsigned* __restrict__ parts, const unsigned* __restrict__ bcount,
    const int* __restrict__ topk,
    unsigned* __restrict__ row_b, unsigned* __restrict__ row_r,
    unsigned* __restrict__ row_ok)
{
    __shared__ unsigned h[TBINS];
    int row = blockIdx.x;
    const unsigned* base = parts + (size_t)row * HBLK * TBINS;
    for (int i = threadIdx.x; i < TBINS; i += blockDim.x) {
        unsigned s = 0;
        #pragma unroll
        for (int p = 0; p < HBLK; ++p) s += base[(size_t)p * TBINS + i];
        h[i] = s;
    }
    __syncthreads();

    if (threadIdx.x == 0) {
        unsigned over = 0;
        #pragma unroll
        for (int p = 0; p < HBLK; ++p) over |= bcount[row * HBLK + p] & OVERFLAG;
        unsigned K = (unsigned)(*topk);
        unsigned acc = 0;
        int b = TBINS - 1, found = 0;
        for (; b >= 0; --b) {
            if (acc + h[b] >= K) { found = 1; break; }
            acc += h[b];
        }
        unsigned okf = 0;
        if (found) {
            unsigned bstar = (unsigned)b + TB_BASE;
            row_b[row] = bstar;
            row_r[row] = K - acc;                        // acc = count strictly above
            okf = (bstar >= G_COLLECT && !over) ? 1u : 0u;
        }
        row_ok[row] = okf;                               // fully overwritten each call
    }
}

// Pass C: per-row block streams the 8 cand slabs: bin>b* -> scatter into out;
// bin==b* -> LDS collect; then exact rank-select in LDS. Writes row_fb always.
__global__ __launch_bounds__(256) void compact_select_kernel(
    const unsigned* __restrict__ bcount, const uint2* __restrict__ cand,
    unsigned cap, const unsigned* __restrict__ row_ok,
    const unsigned* __restrict__ row_b, const unsigned* __restrict__ row_r,
    unsigned* __restrict__ row_fb, float* __restrict__ out, int n_per_row)
{
    __shared__ uint2 sel[LDS_SEL];
    __shared__ unsigned scnt;
    int row = blockIdx.x;
    unsigned fb = 1;
    if (row_ok[row]) {
        unsigned bstar = row_b[row];
        unsigned r = row_r[row];
        float* orow = out + (size_t)row * n_per_row;
        if (threadIdx.x == 0) scnt = 0;
        __syncthreads();
        for (int p = 0; p < HBLK; ++p) {
            unsigned n = bcount[row * HBLK + p] & ~OVERFLAG;
            const uint2* cp = cand + (size_t)(row * HBLK + p) * cap;
            for (unsigned i = threadIdx.x; i < n; i += blockDim.x) {
                uint2 e = cp[i];
                unsigned bin = clamped_bin(e.x);
                if (bin > bstar) {
                    orow[e.y] = __uint_as_float(e.x);    // idempotent w/ fallback
                } else if (bin == bstar) {
                    unsigned pos = atomicAdd(&scnt, 1u); // LDS atomic
                    if (pos < LDS_SEL) sel[pos] = e;
                }
            }
        }
        __syncthreads();
        unsigned M = scnt;
        if (M <= LDS_SEL) {
            rank_select(sel, M, r, orow);
            fb = 0;
        }
    }
    if (threadIdx.x == 0) row_fb[row] = fb;              // fully overwritten
}

// Pass D: exact per-row fallback, one block/row; early-exit unless row_fb.
// Level 0: 12-bit bin hist; level 1: +11 bits; level 2: +8 bits (full absbits);
// final: ordered index scan for exact-value ties. Exact for ANY input.
__global__ __launch_bounds__(256) void fallback_kernel(
    const float* __restrict__ x, const int* __restrict__ topk,
    const unsigned* __restrict__ row_fb, float* __restrict__ out, int n_per_row)
{
    int row = blockIdx.x;
    if (!row_fb[row]) return;

    __shared__ unsigned h[4096];                         // 16 KB (reused per level)
    __shared__ uint2 sel[LDS_SEL];                       // 16 KB
    __shared__ unsigned sb, sr, scnt, runbase;
    __shared__ unsigned sc[256];
    const float* xr = x + (size_t)row * n_per_row;
    float* orow = out + (size_t)row * n_per_row;
    unsigned K = (unsigned)(*topk);

    // ---- level 0: full 12-bit bin histogram ----
    for (int i = threadIdx.x; i < 4096; i += blockDim.x) h[i] = 0;
    __syncthreads();
    for (int i = threadIdx.x; i < n_per_row; i += blockDim.x)
        atomicAdd(&h[(__float_as_uint(xr[i]) & 0x7fffffffu) >> 19], 1u);
    __syncthreads();
    if (threadIdx.x == 0) {
        unsigned acc = 0; int b = 4095;
        for (; b > 0; --b) { if (acc + h[b] >= K) break; acc += h[b]; }
        sb = (unsigned)b; sr = K - acc; scnt = 0;
    }
    __syncthreads();
    unsigned bstar = sb, r = sr;
    for (int i = threadIdx.x; i < n_per_row; i += blockDim.x) {
        unsigned bits = __float_as_uint(xr[i]);
        unsigned bin = (bits & 0x7fffffffu) >> 19;
        if (bin > bstar) orow[i] = __uint_as_float(bits);
        else if (bin == bstar) {
            unsigned p = atomicAdd(&scnt, 1u);
            if (p < LDS_SEL) sel[p] = make_uint2(bits, (unsigned)i);
        }
    }
    __syncthreads();
    if (scnt <= LDS_SEL) { rank_select(sel, scnt, r, orow); return; }

    // ---- level 1: refine by bits 18..8 among bin==bstar ----
    for (int i = threadIdx.x; i < 2048; i += blockDim.x) h[i] = 0;
    __syncthreads();
    for (int i = threadIdx.x; i < n_per_row; i += blockDim.x) {
        unsigned bits = __float_as_uint(xr[i]);
        if (((bits & 0x7fffffffu) >> 19) == bstar)
            atomicAdd(&h[(bits >> 8) & 0x7ffu], 1u);
    }
    __syncthreads();
    if (threadIdx.x == 0) {
        unsigned acc = 0; int s = 2047;
        for (; s > 0; --s) { if (acc + h[s] >= r) break; acc += h[s]; }
        sb = (unsigned)s; sr = r - acc; scnt = 0;
    }
    __syncthreads();
    unsigned s1 = sb; r = sr;
    for (int i = threadIdx.x; i < n_per_row; i += blockDim.x) {
        unsigned bits = __float_as_uint(xr[i]);
        if (((bits & 0x7fffffffu) >> 19) != bstar) continue;
        unsigned sub = (bits >> 8) & 0x7ffu;
        if (sub > s1) orow[i] = __uint_as_float(bits);
        else if (sub == s1) {
            unsigned p = atomicAdd(&scnt, 1u);
            if (p < LDS_SEL) sel[p] = make_uint2(bits, (unsigned)i);
        }
    }
    __syncthreads();
    if (scnt <= LDS_SEL) { rank_select(sel, scnt, r, orow); return; }

    // ---- level 2: refine by last 8 bits ----
    for (int i = threadIdx.x; i < 256; i += blockDim.x) h[i] = 0;
    __syncthreads();
    for (int i = threadIdx.x; i < n_per_row; i += blockDim.x) {
        unsigned bits = __float_as_uint(xr[i]);
        if (((bits & 0x7fffffffu) >> 19) == bstar && ((bits >> 8) & 0x7ffu) == s1)
            atomicAdd(&h[bits & 0xffu], 1u);
    }
    __syncthreads();
    if (threadIdx.x == 0) {
        unsigned acc = 0; int s = 255;
        for (; s > 0; --s) { if (acc + h[s] >= r) break; acc += h[s]; }
        sb = (unsigned)s; sr = r - acc; scnt = 0;
    }
    __syncthreads();
    unsigned s2 = sb; r = sr;
    for (int i = threadIdx.x; i < n_per_row; i += blockDim.x) {
        unsigned bits = __float_as_uint(xr[i]);
        if (((bits & 0x7fffffffu) >> 19) != bstar || ((bits >> 8) & 0x7ffu) != s1)
            continue;
        unsigned sub = bits & 0xffu;
        if (sub > s2) orow[i] = __uint_as_float(bits);
        else if (sub == s2) {
            unsigned p = atomicAdd(&scnt, 1u);
            if (p < LDS_SEL) sel[p] = make_uint2(bits, (unsigned)i);
        }
    }
    __syncthreads();
    if (scnt <= LDS_SEL) { rank_select(sel, scnt, r, orow); return; }

    // ---- exact-value ties beyond LDS: take r smallest indices, in order ----
    unsigned tabs = ((bstar << 19) | (s1 << 8) | s2) & 0x7fffffffu;
    if (threadIdx.x == 0) runbase = 0;
    __syncthreads();
    for (int base = 0; base < n_per_row; base += 256) {
        if (runbase >= r) break;                          // uniform (post-sync read)
        int i = base + (int)threadIdx.x;
        unsigned bits = 0, m = 0;
        if (i < n_per_row) {
            bits = __float_as_uint(xr[i]);
            m = ((bits & 0x7fffffffu) == tabs) ? 1u : 0u;
        }
        sc[threadIdx.x] = m;
        __syncthreads();
        for (int st = 1; st < 256; st <<= 1) {            // inclusive scan
            unsigned v = (threadIdx.x >= (unsigned)st) ? sc[threadIdx.x - st] : 0u;
            __syncthreads();
            sc[threadIdx.x] += v;
            __syncthreads();
        }
        unsigned excl = sc[threadIdx.x] - m;
        if (m && (runbase + excl) < r) orow[i] = __uint_as_float(bits);
        __syncthreads();
        if (threadIdx.x == 0) runbase += sc[255];
        __syncthreads();
    }
}

extern "C" void kernel_launch(void* const* d_in, const int* in_sizes, int n_in,
                              void* d_out, int out_size, void* d_ws, size_t ws_size,
                              hipStream_t stream) {
    const float* x  = (const float*)d_in[0];
    const int* topk = (const int*)d_in[1];
    float* out      = (float*)d_out;

    const int rows = ROWS;
    const int n_per_row = out_size / rows;               // 1,048,576 elements/row

    // --- workspace layout (strictly within ws_size; nothing accumulates) ---
    uint8_t* ws = (uint8_t*)d_ws;
    size_t off = 0;
    unsigned* parts  = (unsigned*)(ws + off);
    off += (size_t)NBLKS * TBINS * sizeof(unsigned);     // 1 MiB
    unsigned* bcount = (unsigned*)(ws + off); off += (NBLKS * 4 + 255) & ~255u;
    unsigned* row_b  = (unsigned*)(ws + off); off += 256;
    unsigned* row_r  = (unsigned*)(ws + off); off += 256;
    unsigned* row_ok = (unsigned*)(ws + off); off += 256;
    unsigned* row_fb = (unsigned*)(ws + off); off += 256;
    off = (off + 255) & ~(size_t)255;

    size_t avail = (ws_size > off) ? (ws_size - off) : 0;
    size_t per_blk = avail / ((size_t)NBLKS * sizeof(uint2));
    unsigned cap = (per_blk > CAP_DEF) ? CAP_DEF : (unsigned)per_blk;
    if (cap == 0) cap = 1;                               // all rows -> fallback, exact
    uint2* cand = (uint2*)(ws + off);

    // 4 dispatches, 0 memsets (out zeroed inside pass A; all ws plain-stored)
    hist_collect_kernel<<<NBLKS, 512, 0, stream>>>(x, out, parts, bcount, cand,
                                                   cap, n_per_row);
    cutoff_kernel<<<rows, 256, 0, stream>>>(parts, bcount, topk, row_b, row_r, row_ok);
    compact_select_kernel<<<rows, 256, 0, stream>>>(bcount, cand, cap, row_ok,
                                                    row_b, row_r, row_fb, out, n_per_row);
    fallback_kernel<<<rows, 256, 0, stream>>>(x, topk, row_fb, out, n_per_row);
}